// Round 15
// baseline (112.243 us; speedup 1.0000x reference)
//
#include <hip/hip_runtime.h>

#define MD   4
#define B_   4
#define C_   128
#define H_   128
#define W_   256
#define ND   9             // 2*MD+1 displacements per axis
#define NW   9             // waves per block, one per dy
#define XPT  8             // x pixels per lane; 32 lanes cover W, 2 rows/wave
#define CC   4             // channels per phase
#define NPH  (C_ / CC)     // 32 phases
#define NRW  12            // rows per channel slab: 2 t1 + 10 t2

typedef float float4v __attribute__((ext_vector_type(4)));

// One block per CU owns (b, y-pair) and ALL 9 dy. Both tensors staged in
// LDS once per block: global line-touches/CU/channel drop 594 -> 202 (the
// one quantity constant across R4-R14, all pinned at 76-80us). Consumption
// is pure LDS; staging is fire-and-forget gload_lds, double-buffered,
// stage-before-compute (drain covered by ~1260cy of FMAs per phase).
// LDS rows use an even/odd 16B-block interleave: logical block j at phys
// (j even: j/2, j odd: 32+j/2), making every window read (logical blocks
// 2lx-1..2lx+2) a stride-1 phys access = conflict-free. Staging applies
// the inverse permutation on the per-lane GLOBAL source (both-sides rule).
__global__ __launch_bounds__(NW * 64, 2)
void corr_kernel(const float* __restrict__ t1,
                 const float* __restrict__ t2,
                 float* __restrict__ out) {
    __shared__ __align__(16) float lds[2][CC][NRW][W_];   // 98304 B

    const int tid  = threadIdx.x;
    const int lane = tid & 63;
    const int w    = tid >> 6;                 // wave id == dy
    const int bid  = blockIdx.x;               // 256 blocks = 8 XCD * 32
    const int swz  = (bid & 7) * 32 + (bid >> 3);
    const int yp   = swz & 63;                 // y-pair index
    const int b    = swz >> 6;                 // 0..3
    const int y0   = yp * 2;
    const int half = lane >> 5;                // 0: row y0, 1: row y0+1
    const int lx   = lane & 31;
    const int x0   = lx * XPT;                 // 0..248
    const int yrow = y0 + half;                // t1/out row
    const int yy   = yrow + w - MD;            // t2 row (may be OOB)
    const bool live = (0 <= yy) && (yy < H_);
    const float sc = live ? (1.0f / (float)C_) : 0.0f;
    const bool lm  = (lx == 0);                // left halo is pad-zero
    const bool rm  = (lx == 31);               // right halo is pad-zero
    const int lxm  = lm ? 0  : lx - 1;         // clamped window indices
    const int lxp  = rm ? lx : lx + 1;
    // staging source block for dest phys block = lane (inverse of even/odd)
    const int jsrc = ((lane & 31) << 1) | (lane >> 5);

    float acc[ND][XPT];
    #pragma unroll
    for (int dx = 0; dx < ND; ++dx)
        #pragma unroll
        for (int j = 0; j < XPT; ++j) acc[dx][j] = 0.0f;

    // stage CC channel-slabs (2 t1 rows + 10 t2 rows each) of phase ph
    auto STAGE = [&](int buf, int ph) {
        const int c0 = ph * CC;
        #pragma unroll
        for (int k = 0; k < 6; ++k) {
            const int s = w + k * NW;          // wave-uniform slot
            if (s < CC * NRW) {
                const int ch = s / NRW;
                const int r  = s % NRW;
                const float* src;
                if (r < 2) {                   // t1 row y0+r
                    src = t1 + (((size_t)(b * C_ + c0 + ch)) * H_ + (y0 + r)) * W_
                            + jsrc * 4;
                } else {                       // t2 row y0 + (r-2) - 4, clamped
                    int gr = y0 + r - 6;
                    gr = gr < 0 ? 0 : (gr > H_ - 1 ? H_ - 1 : gr);
                    src = t2 + (((size_t)(b * C_ + c0 + ch)) * H_ + gr) * W_
                            + jsrc * 4;
                }
                __builtin_amdgcn_global_load_lds(
                    (const __attribute__((address_space(1))) unsigned int*)src,
                    (__attribute__((address_space(3))) unsigned int*)&lds[buf][ch][r][0],
                    16, 0, 0);
            }
        }
    };

    STAGE(0, 0);
    __syncthreads();                            // phase 0 staged

    for (int t = 0; t < NPH; ++t) {
        const int buf = t & 1;
        if (t + 1 < NPH) STAGE(buf ^ 1, t + 1); // in flight under compute

        for (int ch = 0; ch < CC; ++ch) {
            const float* s1 = &lds[buf][ch][half][0];          // t1 row
            const float* s2 = &lds[buf][ch][2 + w + half][0];  // t2 row
            // phys stride-1 b128 reads (even/odd layout)
            const float4v a0 = *(const float4v*)(s1 + lx * 4);        // blk 2lx
            const float4v a1 = *(const float4v*)(s1 + 128 + lx * 4);  // blk 2lx+1
            const float4v v0 = *(const float4v*)(s2 + lx * 4);
            const float4v v1 = *(const float4v*)(s2 + 128 + lx * 4);
            float4v wl = *(const float4v*)(s2 + 128 + lxm * 4);       // blk 2lx-1
            float4v wr = *(const float4v*)(s2 + lxp * 4);             // blk 2lx+2
            #pragma unroll
            for (int q = 0; q < 4; ++q) {
                wl[q] = lm ? 0.0f : wl[q];
                wr[q] = rm ? 0.0f : wr[q];
            }

            float win[XPT + 2 * MD];
            #pragma unroll
            for (int q = 0; q < 4; ++q) {
                win[q]      = wl[q];
                win[4 + q]  = v0[q];
                win[8 + q]  = v1[q];
                win[12 + q] = wr[q];
            }

            #pragma unroll
            for (int dx = 0; dx < ND; ++dx)
                #pragma unroll
                for (int j = 0; j < XPT; ++j) {
                    const float aj = (j < 4) ? a0[j] : a1[j - 4];
                    acc[dx][j] = fmaf(aj, win[dx + j], acc[dx][j]);
                }
        }
        __syncthreads();   // next phase landed; all waves done with buf
    }

    #pragma unroll
    for (int dx = 0; dx < ND; ++dx) {
        float4v o0, o1;
        #pragma unroll
        for (int j = 0; j < 4; ++j) {
            o0[j] = acc[dx][j]     * sc;
            o1[j] = acc[dx][4 + j] * sc;
        }
        const size_t oidx =
            (((size_t)(b * ND * ND) + w * ND + dx) * H_ + yrow) * W_ + x0;
        *(float4v*)&out[oidx]     = o0;
        *(float4v*)&out[oidx + 4] = o1;
    }
}

extern "C" void kernel_launch(void* const* d_in, const int* in_sizes, int n_in,
                              void* d_out, int out_size, void* d_ws, size_t ws_size,
                              hipStream_t stream) {
    const float* t1 = (const float*)d_in[0];
    const float* t2 = (const float*)d_in[1];
    float* out      = (float*)d_out;
    corr_kernel<<<dim3(B_ * H_ / 2), NW * 64, 0, stream>>>(t1, t2, out);
}